// Round 15
// baseline (471.711 us; speedup 1.0000x reference)
//
#include <hip/hip_runtime.h>
#include <math.h>

typedef __bf16 bf16_t;
typedef bf16_t bf16x8 __attribute__((ext_vector_type(8)));
typedef bf16_t bf16x4 __attribute__((ext_vector_type(4)));
typedef float f32x4 __attribute__((ext_vector_type(4)));
typedef float f32x16 __attribute__((ext_vector_type(16)));

#define BB 4
#define SS 2048
#define HD1 1024
#define NH 16
#define DFF_ 4096

__device__ __forceinline__ void gload_lds16(const bf16_t* g, bf16_t* l) {
  __builtin_amdgcn_global_load_lds(
      (const __attribute__((address_space(1))) void*)g,
      (__attribute__((address_space(3))) void*)l, 16, 0, 0);
}

// single-instruction f32x2 -> packed bf16 (T12 recipe; no builtin on gfx950)
__device__ __forceinline__ unsigned pack2_bf16(float a, float b) {
  unsigned r;
  asm("v_cvt_pk_bf16_f32 %0, %1, %2" : "=v"(r) : "v"(a), "v"(b));
  return r;
}

// ---------------- LayerNorm: fp32 in -> bf16 out, one block per row ---------
__device__ __forceinline__ float block_reduce_sum(float v, float* red) {
  const int lane = threadIdx.x & 63;
  const int wid = threadIdx.x >> 6;
#pragma unroll
  for (int off = 32; off > 0; off >>= 1) v += __shfl_down(v, off, 64);
  if (lane == 0) red[wid] = v;
  __syncthreads();
  float s = red[0] + red[1] + red[2] + red[3];
  __syncthreads();
  return s;
}

__global__ __launch_bounds__(256) void ln_kernel(const float* __restrict__ x,
                                                 const float* __restrict__ w,
                                                 const float* __restrict__ bv,
                                                 bf16_t* __restrict__ out) {
  __shared__ float red[4];
  const size_t row = blockIdx.x;
  const float4 xv = *(const float4*)(x + row * HD1 + threadIdx.x * 4);
  float s = xv.x + xv.y + xv.z + xv.w;
  s = block_reduce_sum(s, red);
  const float mu = s * (1.0f / HD1);
  float4 d;
  d.x = xv.x - mu; d.y = xv.y - mu; d.z = xv.z - mu; d.w = xv.w - mu;
  float sq = d.x * d.x + d.y * d.y + d.z * d.z + d.w * d.w;
  sq = block_reduce_sum(sq, red);
  const float rs = rsqrtf(sq * (1.0f / HD1) + 1e-12f);
  const float4 wv = *(const float4*)(w + threadIdx.x * 4);
  const float4 bb = *(const float4*)(bv + threadIdx.x * 4);
  bf16x4 o;
  o[0] = (bf16_t)(d.x * rs * wv.x + bb.x);
  o[1] = (bf16_t)(d.y * rs * wv.y + bb.y);
  o[2] = (bf16_t)(d.z * rs * wv.z + bb.z);
  o[3] = (bf16_t)(d.w * rs * wv.w + bb.w);
  *(bf16x4*)(out + row * HD1 + threadIdx.x * 4) = o;
}

// ---------------- Weight convert+transpose: W[K][N] f32 -> Wt[N][K] bf16 ----
__global__ __launch_bounds__(256) void wt_kernel(const float* __restrict__ W,
                                                 bf16_t* __restrict__ Wt,
                                                 int K, int N) {
  __shared__ bf16_t T[32][33];
  const int t = threadIdx.x;
  const int n0 = blockIdx.x * 32, k0 = blockIdx.y * 32;
  const int a = t >> 5, c = t & 31;
#pragma unroll
  for (int i = 0; i < 4; ++i) {
    const int kl = a + i * 8;
    T[kl][c] = (bf16_t)W[(size_t)(k0 + kl) * N + n0 + c];
  }
  __syncthreads();
#pragma unroll
  for (int i = 0; i < 4; ++i) {
    const int nl = a + i * 8;
    Wt[(size_t)(n0 + nl) * K + k0 + c] = T[c][nl];
  }
}

// -------- V transpose via LDS: qkv[b][s][2H+h*64+d] -> Vt[b][h][d][s] -------
__global__ __launch_bounds__(256) void vtrans_kernel(const bf16_t* __restrict__ qkv,
                                                     bf16_t* __restrict__ Vt) {
  __shared__ bf16_t T[256 * 66];  // [s][d], stride 66 (2-way max banking)
  const int t = threadIdx.x;
  const int s0 = blockIdx.x * 256;
  const int head = blockIdx.y, b = blockIdx.z;
  const int rr = t >> 3, dc = (t & 7) * 8;
#pragma unroll
  for (int p = 0; p < 8; ++p) {
    const int s = rr + p * 32;
    const bf16x8 v = *(const bf16x8*)(
        qkv + (size_t)(b * SS + s0 + s) * 3072 + 2048 + head * 64 + dc);
    *(bf16x8*)&T[s * 66 + dc] = v;
  }
  __syncthreads();
  const int dd = t >> 3;
  const int sw = (t & 7) * 8;
#pragma unroll
  for (int p = 0; p < 2; ++p) {
    const int d = dd + p * 32;
    bf16_t* dst = Vt + ((size_t)(b * NH + head) * 64 + d) * SS + s0;
#pragma unroll
    for (int j = 0; j < 4; ++j) {
      bf16x8 o;
#pragma unroll
      for (int e = 0; e < 8; ++e) o[e] = T[(sw + j * 64 + e) * 66 + d];
      *(bf16x8*)(dst + sw + j * 64) = o;
    }
  }
}

// ---------------- MFMA GEMM, BK=64 double-buffered + 8-chunk XOR swizzle ----
// (round-10/14 measured best: FFN1 150us, conflicts ~1e6)
template <int EPI, bool OBF>
__global__ __launch_bounds__(256) void gemm_bf16(
    const bf16_t* __restrict__ A, const bf16_t* __restrict__ Wt,
    const float* __restrict__ bias, const float* __restrict__ R,
    void* __restrict__ Cout, int M, int N, int K) {
  __shared__ __align__(16) char smem[65536];
  bf16_t* As = (bf16_t*)smem;              // [2][128*64]
  bf16_t* Bs = (bf16_t*)(smem + 32768);    // [2][128*64]
  const int tid = threadIdx.x;
  const int lane = tid & 63;
  const int w = tid >> 6;
  const int wm = (w >> 1) * 64, wn = (w & 1) * 64;
  const int l15 = lane & 15, l4 = lane >> 4;

  const int gx = gridDim.x;
  int id = blockIdx.x + gx * blockIdx.y;
  const int cpx = (gx * gridDim.y) >> 3;
  id = (id & 7) * cpx + (id >> 3);
  const int m0 = (id / gx) * 128;
  const int n0 = (id % gx) * 128;

  const int lrow = tid >> 3;
  const int lcol = (((tid & 7) ^ ((tid >> 3) & 7)) * 8);
  const bf16_t* Ag = A + (size_t)(m0 + lrow) * K + lcol;
  const bf16_t* Bg = Wt + (size_t)(n0 + lrow) * K + lcol;
  const size_t rstride = (size_t)32 * K;

#pragma unroll
  for (int c = 0; c < 4; ++c) {
    gload_lds16(Ag + c * rstride, As + c * 2048 + w * 512);
    gload_lds16(Bg + c * rstride, Bs + c * 2048 + w * 512);
  }

  const int NT = K >> 6;
  f32x4 acc[4][4] = {};

  const int ch0 = (((0 * 4 + l4) ^ (l15 & 7)) * 8);
  const int ch1 = (((1 * 4 + l4) ^ (l15 & 7)) * 8);

  for (int t = 0; t < NT; ++t) {
    const int cur = t & 1;
    __syncthreads();
    if (t + 1 < NT) {
      const bf16_t* Agn = Ag + (size_t)(t + 1) * 64;
      const bf16_t* Bgn = Bg + (size_t)(t + 1) * 64;
      bf16_t* Ad = As + (cur ^ 1) * 8192;
      bf16_t* Bd = Bs + (cur ^ 1) * 8192;
#pragma unroll
      for (int c = 0; c < 4; ++c) {
        gload_lds16(Agn + c * rstride, Ad + c * 2048 + w * 512);
        gload_lds16(Bgn + c * rstride, Bd + c * 2048 + w * 512);
      }
    }
    const bf16_t* Ab = As + cur * 8192;
    const bf16_t* Bb = Bs + cur * 8192;
    bf16x8 af[2][4], bfr[2][4];
#pragma unroll
    for (int i = 0; i < 4; ++i) {
      af[0][i] = *(const bf16x8*)(Ab + (wm + i * 16 + l15) * 64 + ch0);
      af[1][i] = *(const bf16x8*)(Ab + (wm + i * 16 + l15) * 64 + ch1);
    }
#pragma unroll
    for (int j = 0; j < 4; ++j) {
      bfr[0][j] = *(const bf16x8*)(Bb + (wn + j * 16 + l15) * 64 + ch0);
      bfr[1][j] = *(const bf16x8*)(Bb + (wn + j * 16 + l15) * 64 + ch1);
    }
#pragma unroll
    for (int ks = 0; ks < 2; ++ks)
#pragma unroll
      for (int i = 0; i < 4; ++i)
#pragma unroll
        for (int j = 0; j < 4; ++j)
          acc[i][j] = __builtin_amdgcn_mfma_f32_16x16x32_bf16(
              af[ks][i], bfr[ks][j], acc[i][j], 0, 0, 0);
  }

  if (OBF) {
    __syncthreads();
    float* Cs = (float*)smem;  // 128 x 128 f32 = 64 KiB
#pragma unroll
    for (int j = 0; j < 4; ++j) {
      const float bj = bias[n0 + wn + j * 16 + l15];
#pragma unroll
      for (int i = 0; i < 4; ++i)
#pragma unroll
        for (int r = 0; r < 4; ++r) {
          float v = acc[i][j][r] + bj;
          if (EPI == 1)
            v = 0.5f * v * (1.0f + erff(v * 0.70710678118654752440f));
          Cs[(wm + i * 16 + l4 * 4 + r) * 128 + wn + j * 16 + l15] = v;
        }
    }
    __syncthreads();
    bf16_t* Cb = (bf16_t*)Cout;
#pragma unroll
    for (int p = 0; p < 16; ++p) {
      const int idx = p * 256 + tid;
      const int row = idx >> 5, c4 = idx & 31;
      const f32x4 v = *(const f32x4*)(Cs + row * 128 + c4 * 4);
      bf16x4 o;
      o[0] = (bf16_t)v[0]; o[1] = (bf16_t)v[1];
      o[2] = (bf16_t)v[2]; o[3] = (bf16_t)v[3];
      *(bf16x4*)(Cb + (size_t)(m0 + row) * N + n0 + c4 * 4) = o;
    }
  } else {
    float* Cf = (float*)Cout;
#pragma unroll
    for (int j = 0; j < 4; ++j) {
      const int gn = n0 + wn + j * 16 + l15;
      const float bj = bias[gn];
#pragma unroll
      for (int i = 0; i < 4; ++i) {
        const int gm = m0 + wm + i * 16 + l4 * 4;
#pragma unroll
        for (int r = 0; r < 4; ++r) {
          float v = acc[i][j][r] + bj;
          if (EPI == 2) v += R[(size_t)(gm + r) * N + gn];
          Cf[(size_t)(gm + r) * N + gn] = v;
        }
      }
    }
  }
}

// ------- MFMA flash attention: KVB=128 (one barrier pair / 128 kv rows) -----
// Grid: 1024 blocks 1D, XCD-grouping decode (K/V pinned per-XCD L2).
// Two compute sub-steps per staged tile; T14 reg-prefetch of next 128 rows.
__global__ __launch_bounds__(256, 3) void attn_kernel(
    const bf16_t* __restrict__ qkv, const bf16_t* __restrict__ Vt,
    const float* __restrict__ mask, bf16_t* __restrict__ ctx) {
  __shared__ __align__(16) bf16_t K_lds[128 * 72];   // [kv][d]   18.4KB
  __shared__ __align__(16) bf16_t Vt_lds[64 * 136];  // [dv][kv]  17.4KB
  const int tid = threadIdx.x;
  const int lane = tid & 63;
  const int w = tid >> 6;
  const int l31 = lane & 31;
  const int h = lane >> 5;

  // XCD-grouping decode (bijective on 1024 blocks)
  const int p = blockIdx.x;
  const int xcd = p & 7;
  const int c = p >> 3;
  const int j = c & 15;
  const int g = (c >> 4) * 8 + xcd;
  const int b = g >> 4;
  const int head = g & 15;
  const int q0 = j * 128;

  const int qrow = q0 + w * 32 + l31;

  bf16x8 qf[4];
  {
    const bf16_t* qp = qkv + (size_t)(b * SS + qrow) * 3072 + head * 64 + 8 * h;
#pragma unroll
    for (int ks = 0; ks < 4; ++ks) qf[ks] = *(const bf16x8*)(qp + 16 * ks);
  }

  const int srow = tid >> 2;          // 0..63
  const int scol = (tid & 3) * 16;    // K col offset (elems)
  const int vcol = (tid & 3) * 32;    // V kv offset (elems)
  const bf16_t* kp0 =
      qkv + (size_t)(b * SS + srow) * 3072 + 1024 + head * 64 + scol;
  const bf16_t* vp0 = Vt + ((size_t)(b * NH + head) * 64 + srow) * SS + vcol;
  const size_t krstep = (size_t)64 * 3072;  // +64 kv rows

  // prologue: load K/V tile 0 (128 kv rows) into registers
  bf16x8 kr0 = *(const bf16x8*)kp0;
  bf16x8 kr1 = *(const bf16x8*)(kp0 + 8);
  bf16x8 kr2 = *(const bf16x8*)(kp0 + krstep);
  bf16x8 kr3 = *(const bf16x8*)(kp0 + krstep + 8);
  bf16x8 vr0 = *(const bf16x8*)vp0;
  bf16x8 vr1 = *(const bf16x8*)(vp0 + 8);
  bf16x8 vr2 = *(const bf16x8*)(vp0 + 16);
  bf16x8 vr3 = *(const bf16x8*)(vp0 + 24);

  float m = -3.0e38f, l = 0.0f;
  f32x16 cacc0 = {};
  f32x16 cacc1 = {};

  for (int kv0 = 0; kv0 < SS; kv0 += 128) {
    __syncthreads();  // all waves done reading previous K/V tile
    *(bf16x8*)(K_lds + srow * 72 + scol) = kr0;
    *(bf16x8*)(K_lds + srow * 72 + scol + 8) = kr1;
    *(bf16x8*)(K_lds + (srow + 64) * 72 + scol) = kr2;
    *(bf16x8*)(K_lds + (srow + 64) * 72 + scol + 8) = kr3;
    *(bf16x8*)(Vt_lds + srow * 136 + vcol) = vr0;
    *(bf16x8*)(Vt_lds + srow * 136 + vcol + 8) = vr1;
    *(bf16x8*)(Vt_lds + srow * 136 + vcol + 16) = vr2;
    *(bf16x8*)(Vt_lds + srow * 136 + vcol + 24) = vr3;
    // T14: issue NEXT tile's loads; latency hides under this tile's compute
    if (kv0 + 128 < SS) {
      const bf16_t* kp = kp0 + (size_t)(kv0 + 128) * 3072;
      const bf16_t* vp = vp0 + (kv0 + 128);
      kr0 = *(const bf16x8*)kp;
      kr1 = *(const bf16x8*)(kp + 8);
      kr2 = *(const bf16x8*)(kp + krstep);
      kr3 = *(const bf16x8*)(kp + krstep + 8);
      vr0 = *(const bf16x8*)vp;
      vr1 = *(const bf16x8*)(vp + 8);
      vr2 = *(const bf16x8*)(vp + 16);
      vr3 = *(const bf16x8*)(vp + 24);
    }
    __syncthreads();

#pragma unroll
    for (int s = 0; s < 2; ++s) {
      const int kvo = s * 64;
      float4 mv[8];
#pragma unroll
      for (int k2 = 0; k2 < 8; ++k2)
        mv[k2] = *(const float4*)(mask + (size_t)b * SS + kv0 + kvo + 8 * k2 +
                                  4 * h);

      f32x16 sacc0 = {};
      f32x16 sacc1 = {};
#pragma unroll
      for (int ks = 0; ks < 4; ++ks) {
        const bf16x8 kf0 =
            *(const bf16x8*)(K_lds + (kvo + l31) * 72 + 16 * ks + 8 * h);
        const bf16x8 kf1 =
            *(const bf16x8*)(K_lds + (kvo + l31 + 32) * 72 + 16 * ks + 8 * h);
        sacc0 = __builtin_amdgcn_mfma_f32_32x32x16_bf16(kf0, qf[ks], sacc0, 0, 0, 0);
        sacc1 = __builtin_amdgcn_mfma_f32_32x32x16_bf16(kf1, qf[ks], sacc1, 0, 0, 0);
      }

      float ps[32];
      float tmax = -3.0e38f;
#pragma unroll
      for (int r = 0; r < 16; ++r) {
        const float s0 = sacc0[r] * 0.125f + mv[(r >> 2)][r & 3];
        const float s1 = sacc1[r] * 0.125f + mv[(r >> 2) + 4][r & 3];
        ps[r] = s0;
        ps[16 + r] = s1;
        tmax = fmaxf(tmax, fmaxf(s0, s1));
      }
      tmax = fmaxf(tmax, __shfl_xor(tmax, 32, 64));
      if (__any(tmax > m + 8.0f)) {
        const float mnew = fmaxf(m, tmax);
        const float sc = __expf(m - mnew);
        m = mnew;
        l *= sc;
#pragma unroll
        for (int r = 0; r < 16; ++r) {
          const float scr = __shfl(sc, (r & 3) + 8 * (r >> 2) + 4 * h, 64);
          cacc0[r] *= scr;
          cacc1[r] *= scr;
        }
      }
      float ls = 0.0f;
#pragma unroll
      for (int i = 0; i < 32; ++i) {
        ps[i] = __expf(ps[i] - m);
        ls += ps[i];
      }
      l += ls + __shfl_xor(ls, 32, 64);

      unsigned pw0[8], pw1[8];
#pragma unroll
      for (int k = 0; k < 8; ++k) {
        const int base = (k >> 2) * 16 + (k & 3) * 4;
        pw0[k] = pack2_bf16(ps[base + 0], ps[base + 1]);
        pw1[k] = pack2_bf16(ps[base + 2], ps[base + 3]);
      }
#pragma unroll
      for (int t = 0; t < 4; ++t) {
        const unsigned e0 = h ? pw0[2 * t] : pw0[2 * t + 1];
        const unsigned e1 = h ? pw1[2 * t] : pw1[2 * t + 1];
        const unsigned o0 = (unsigned)__shfl_xor((int)e0, 32, 64);
        const unsigned o1 = (unsigned)__shfl_xor((int)e1, 32, 64);
        const unsigned a0 = h ? pw0[2 * t + 1] : pw0[2 * t];
        const unsigned a1 = h ? pw1[2 * t + 1] : pw1[2 * t];
        union { unsigned u[4]; bf16x8 v; } pu;
        pu.u[0] = h ? o0 : a0;
        pu.u[1] = h ? o1 : a1;
        pu.u[2] = h ? a0 : o0;
        pu.u[3] = h ? a1 : o1;
        const bf16x8 vf0 =
            *(const bf16x8*)(Vt_lds + l31 * 136 + kvo + 16 * t + 8 * h);
        const bf16x8 vf1 =
            *(const bf16x8*)(Vt_lds + (l31 + 32) * 136 + kvo + 16 * t + 8 * h);
        cacc0 = __builtin_amdgcn_mfma_f32_32x32x16_bf16(pu.v, vf0, cacc0, 0, 0, 0);
        cacc1 = __builtin_amdgcn_mfma_f32_32x32x16_bf16(pu.v, vf1, cacc1, 0, 0, 0);
      }
    }
  }

  const float linv = 1.0f / l;
#pragma unroll
  for (int r = 0; r < 16; ++r) {
    const int rq = (r & 3) + 8 * (r >> 2) + 4 * h;
    const float li = __shfl(linv, rq, 64);
    const int grow = q0 + w * 32 + rq;
    bf16_t* op = ctx + (size_t)(b * SS + grow) * 1024 + head * 64 + l31;
    op[0] = (bf16_t)(cacc0[r] * li);
    op[32] = (bf16_t)(cacc1[r] * li);
  }
}

extern "C" void kernel_launch(void* const* d_in, const int* in_sizes, int n_in,
                              void* d_out, int out_size, void* d_ws, size_t ws_size,
                              hipStream_t stream) {
  const float* input    = (const float*)d_in[0];
  const float* mask     = (const float*)d_in[1];
  const float* norm_w   = (const float*)d_in[2];
  const float* norm_b   = (const float*)d_in[3];
  const float* qkv_w    = (const float*)d_in[4];
  const float* qkv_b    = (const float*)d_in[5];
  const float* attn_ow  = (const float*)d_in[6];
  const float* attn_ob  = (const float*)d_in[7];
  const float* attn_nw  = (const float*)d_in[8];
  const float* attn_nb  = (const float*)d_in[9];
  const float* inter_w  = (const float*)d_in[10];
  const float* inter_b  = (const float*)d_in[11];
  const float* output_w = (const float*)d_in[12];
  const float* output_b = (const float*)d_in[13];

  char* ws = (char*)d_ws;
  const size_t off_xln = 0;
  const size_t off_qkv = 16777216;
  const size_t off_vt  = 67108864;
  const size_t off_ctx = 83886080;
  const size_t off_ao  = 100663296;
  const size_t off_wq  = 134217728;
  const size_t off_wo  = 140509184;
  const size_t off_wi  = 142606336;
  const size_t off_w2  = 150994944;
  const size_t NEED    = 159383552;
  if (ws_size < NEED) return;

  bf16_t* x_ln  = (bf16_t*)(ws + off_xln);
  bf16_t* qkvb  = (bf16_t*)(ws + off_qkv);
  bf16_t* VtB   = (bf16_t*)(ws + off_vt);
  bf16_t* ctxb  = (bf16_t*)(ws + off_ctx);
  bf16_t* y_ln  = (bf16_t*)(ws + off_ctx);
  float*  a_out = (float*)(ws + off_ao);
  bf16_t* wq_t  = (bf16_t*)(ws + off_wq);
  bf16_t* wo_t  = (bf16_t*)(ws + off_wo);
  bf16_t* wi_t  = (bf16_t*)(ws + off_wi);
  bf16_t* w2_t  = (bf16_t*)(ws + off_w2);
  bf16_t* act   = (bf16_t*)(ws + off_xln);

  const int M = BB * SS;  // 8192

  wt_kernel<<<dim3(3072 / 32, 1024 / 32), 256, 0, stream>>>(qkv_w, wq_t, 1024, 3072);
  wt_kernel<<<dim3(1024 / 32, 1024 / 32), 256, 0, stream>>>(attn_ow, wo_t, 1024, 1024);
  wt_kernel<<<dim3(4096 / 32, 1024 / 32), 256, 0, stream>>>(inter_w, wi_t, 1024, 4096);
  wt_kernel<<<dim3(1024 / 32, 4096 / 32), 256, 0, stream>>>(output_w, w2_t, 4096, 1024);

  ln_kernel<<<M, 256, 0, stream>>>(input, norm_w, norm_b, x_ln);
  gemm_bf16<0, true><<<dim3(3072 / 128, M / 128), 256, 0, stream>>>(
      x_ln, wq_t, qkv_b, nullptr, qkvb, M, 3072, 1024);
  vtrans_kernel<<<dim3(SS / 256, NH, BB), 256, 0, stream>>>(qkvb, VtB);
  attn_kernel<<<1024, 256, 0, stream>>>(qkvb, VtB, mask, ctxb);
  gemm_bf16<2, false><<<dim3(1024 / 128, M / 128), 256, 0, stream>>>(
      ctxb, wo_t, attn_ob, input, a_out, M, 1024, 1024);
  ln_kernel<<<M, 256, 0, stream>>>(a_out, attn_nw, attn_nb, y_ln);
  gemm_bf16<1, true><<<dim3(4096 / 128, M / 128), 256, 0, stream>>>(
      y_ln, wi_t, inter_b, nullptr, act, M, 4096, 1024);
  gemm_bf16<2, false><<<dim3(1024 / 128, M / 128), 256, 0, stream>>>(
      act, w2_t, output_b, a_out, (float*)d_out, M, 1024, 4096);
}

// Round 16
// 461.889 us; speedup vs baseline: 1.0213x; 1.0213x over previous
//
#include <hip/hip_runtime.h>
#include <math.h>

typedef __bf16 bf16_t;
typedef bf16_t bf16x8 __attribute__((ext_vector_type(8)));
typedef bf16_t bf16x4 __attribute__((ext_vector_type(4)));
typedef float f32x4 __attribute__((ext_vector_type(4)));
typedef float f32x16 __attribute__((ext_vector_type(16)));

#define BB 4
#define SS 2048
#define HD1 1024
#define NH 16
#define DFF_ 4096

__device__ __forceinline__ void gload_lds16(const bf16_t* g, bf16_t* l) {
  __builtin_amdgcn_global_load_lds(
      (const __attribute__((address_space(1))) void*)g,
      (__attribute__((address_space(3))) void*)l, 16, 0, 0);
}

// single-instruction f32x2 -> packed bf16 (T12 recipe; no builtin on gfx950)
__device__ __forceinline__ unsigned pack2_bf16(float a, float b) {
  unsigned r;
  asm("v_cvt_pk_bf16_f32 %0, %1, %2" : "=v"(r) : "v"(a), "v"(b));
  return r;
}

// ---------------- LayerNorm: fp32 in -> bf16 out, one block per row ---------
__device__ __forceinline__ float block_reduce_sum(float v, float* red) {
  const int lane = threadIdx.x & 63;
  const int wid = threadIdx.x >> 6;
#pragma unroll
  for (int off = 32; off > 0; off >>= 1) v += __shfl_down(v, off, 64);
  if (lane == 0) red[wid] = v;
  __syncthreads();
  float s = red[0] + red[1] + red[2] + red[3];
  __syncthreads();
  return s;
}

__global__ __launch_bounds__(256) void ln_kernel(const float* __restrict__ x,
                                                 const float* __restrict__ w,
                                                 const float* __restrict__ bv,
                                                 bf16_t* __restrict__ out) {
  __shared__ float red[4];
  const size_t row = blockIdx.x;
  const float4 xv = *(const float4*)(x + row * HD1 + threadIdx.x * 4);
  float s = xv.x + xv.y + xv.z + xv.w;
  s = block_reduce_sum(s, red);
  const float mu = s * (1.0f / HD1);
  float4 d;
  d.x = xv.x - mu; d.y = xv.y - mu; d.z = xv.z - mu; d.w = xv.w - mu;
  float sq = d.x * d.x + d.y * d.y + d.z * d.z + d.w * d.w;
  sq = block_reduce_sum(sq, red);
  const float rs = rsqrtf(sq * (1.0f / HD1) + 1e-12f);
  const float4 wv = *(const float4*)(w + threadIdx.x * 4);
  const float4 bb = *(const float4*)(bv + threadIdx.x * 4);
  bf16x4 o;
  o[0] = (bf16_t)(d.x * rs * wv.x + bb.x);
  o[1] = (bf16_t)(d.y * rs * wv.y + bb.y);
  o[2] = (bf16_t)(d.z * rs * wv.z + bb.z);
  o[3] = (bf16_t)(d.w * rs * wv.w + bb.w);
  *(bf16x4*)(out + row * HD1 + threadIdx.x * 4) = o;
}

// ---------------- Weight convert+transpose: W[K][N] f32 -> Wt[N][K] bf16 ----
__global__ __launch_bounds__(256) void wt_kernel(const float* __restrict__ W,
                                                 bf16_t* __restrict__ Wt,
                                                 int K, int N) {
  __shared__ bf16_t T[32][33];
  const int t = threadIdx.x;
  const int n0 = blockIdx.x * 32, k0 = blockIdx.y * 32;
  const int a = t >> 5, c = t & 31;
#pragma unroll
  for (int i = 0; i < 4; ++i) {
    const int kl = a + i * 8;
    T[kl][c] = (bf16_t)W[(size_t)(k0 + kl) * N + n0 + c];
  }
  __syncthreads();
#pragma unroll
  for (int i = 0; i < 4; ++i) {
    const int nl = a + i * 8;
    Wt[(size_t)(n0 + nl) * K + k0 + c] = T[c][nl];
  }
}

// -------- V transpose via LDS: qkv[b][s][2H+h*64+d] -> Vt[b][h][d][s] -------
__global__ __launch_bounds__(256) void vtrans_kernel(const bf16_t* __restrict__ qkv,
                                                     bf16_t* __restrict__ Vt) {
  __shared__ bf16_t T[256 * 66];  // [s][d], stride 66 (2-way max banking)
  const int t = threadIdx.x;
  const int s0 = blockIdx.x * 256;
  const int head = blockIdx.y, b = blockIdx.z;
  const int rr = t >> 3, dc = (t & 7) * 8;
#pragma unroll
  for (int p = 0; p < 8; ++p) {
    const int s = rr + p * 32;
    const bf16x8 v = *(const bf16x8*)(
        qkv + (size_t)(b * SS + s0 + s) * 3072 + 2048 + head * 64 + dc);
    *(bf16x8*)&T[s * 66 + dc] = v;
  }
  __syncthreads();
  const int dd = t >> 3;
  const int sw = (t & 7) * 8;
#pragma unroll
  for (int p = 0; p < 2; ++p) {
    const int d = dd + p * 32;
    bf16_t* dst = Vt + ((size_t)(b * NH + head) * 64 + d) * SS + s0;
#pragma unroll
    for (int j = 0; j < 4; ++j) {
      bf16x8 o;
#pragma unroll
      for (int e = 0; e < 8; ++e) o[e] = T[(sw + j * 64 + e) * 66 + d];
      *(bf16x8*)(dst + sw + j * 64) = o;
    }
  }
}

// ---------------- MFMA GEMM, BK=64 double-buffered + 8-chunk XOR swizzle ----
// (round-10/14 measured best: FFN1 150us, conflicts ~1e6)
template <int EPI, bool OBF>
__global__ __launch_bounds__(256) void gemm_bf16(
    const bf16_t* __restrict__ A, const bf16_t* __restrict__ Wt,
    const float* __restrict__ bias, const float* __restrict__ R,
    void* __restrict__ Cout, int M, int N, int K) {
  __shared__ __align__(16) char smem[65536];
  bf16_t* As = (bf16_t*)smem;              // [2][128*64]
  bf16_t* Bs = (bf16_t*)(smem + 32768);    // [2][128*64]
  const int tid = threadIdx.x;
  const int lane = tid & 63;
  const int w = tid >> 6;
  const int wm = (w >> 1) * 64, wn = (w & 1) * 64;
  const int l15 = lane & 15, l4 = lane >> 4;

  const int gx = gridDim.x;
  int id = blockIdx.x + gx * blockIdx.y;
  const int cpx = (gx * gridDim.y) >> 3;
  id = (id & 7) * cpx + (id >> 3);
  const int m0 = (id / gx) * 128;
  const int n0 = (id % gx) * 128;

  const int lrow = tid >> 3;
  const int lcol = (((tid & 7) ^ ((tid >> 3) & 7)) * 8);
  const bf16_t* Ag = A + (size_t)(m0 + lrow) * K + lcol;
  const bf16_t* Bg = Wt + (size_t)(n0 + lrow) * K + lcol;
  const size_t rstride = (size_t)32 * K;

#pragma unroll
  for (int c = 0; c < 4; ++c) {
    gload_lds16(Ag + c * rstride, As + c * 2048 + w * 512);
    gload_lds16(Bg + c * rstride, Bs + c * 2048 + w * 512);
  }

  const int NT = K >> 6;
  f32x4 acc[4][4] = {};

  const int ch0 = (((0 * 4 + l4) ^ (l15 & 7)) * 8);
  const int ch1 = (((1 * 4 + l4) ^ (l15 & 7)) * 8);

  for (int t = 0; t < NT; ++t) {
    const int cur = t & 1;
    __syncthreads();
    if (t + 1 < NT) {
      const bf16_t* Agn = Ag + (size_t)(t + 1) * 64;
      const bf16_t* Bgn = Bg + (size_t)(t + 1) * 64;
      bf16_t* Ad = As + (cur ^ 1) * 8192;
      bf16_t* Bd = Bs + (cur ^ 1) * 8192;
#pragma unroll
      for (int c = 0; c < 4; ++c) {
        gload_lds16(Agn + c * rstride, Ad + c * 2048 + w * 512);
        gload_lds16(Bgn + c * rstride, Bd + c * 2048 + w * 512);
      }
    }
    const bf16_t* Ab = As + cur * 8192;
    const bf16_t* Bb = Bs + cur * 8192;
    bf16x8 af[2][4], bfr[2][4];
#pragma unroll
    for (int i = 0; i < 4; ++i) {
      af[0][i] = *(const bf16x8*)(Ab + (wm + i * 16 + l15) * 64 + ch0);
      af[1][i] = *(const bf16x8*)(Ab + (wm + i * 16 + l15) * 64 + ch1);
    }
#pragma unroll
    for (int j = 0; j < 4; ++j) {
      bfr[0][j] = *(const bf16x8*)(Bb + (wn + j * 16 + l15) * 64 + ch0);
      bfr[1][j] = *(const bf16x8*)(Bb + (wn + j * 16 + l15) * 64 + ch1);
    }
#pragma unroll
    for (int ks = 0; ks < 2; ++ks)
#pragma unroll
      for (int i = 0; i < 4; ++i)
#pragma unroll
        for (int j = 0; j < 4; ++j)
          acc[i][j] = __builtin_amdgcn_mfma_f32_16x16x32_bf16(
              af[ks][i], bfr[ks][j], acc[i][j], 0, 0, 0);
  }

  if (OBF) {
    __syncthreads();
    float* Cs = (float*)smem;  // 128 x 128 f32 = 64 KiB
#pragma unroll
    for (int j = 0; j < 4; ++j) {
      const float bj = bias[n0 + wn + j * 16 + l15];
#pragma unroll
      for (int i = 0; i < 4; ++i)
#pragma unroll
        for (int r = 0; r < 4; ++r) {
          float v = acc[i][j][r] + bj;
          if (EPI == 1)
            v = 0.5f * v * (1.0f + erff(v * 0.70710678118654752440f));
          Cs[(wm + i * 16 + l4 * 4 + r) * 128 + wn + j * 16 + l15] = v;
        }
    }
    __syncthreads();
    bf16_t* Cb = (bf16_t*)Cout;
#pragma unroll
    for (int p = 0; p < 16; ++p) {
      const int idx = p * 256 + tid;
      const int row = idx >> 5, c4 = idx & 31;
      const f32x4 v = *(const f32x4*)(Cs + row * 128 + c4 * 4);
      bf16x4 o;
      o[0] = (bf16_t)v[0]; o[1] = (bf16_t)v[1];
      o[2] = (bf16_t)v[2]; o[3] = (bf16_t)v[3];
      *(bf16x4*)(Cb + (size_t)(m0 + row) * N + n0 + c4 * 4) = o;
    }
  } else {
    float* Cf = (float*)Cout;
#pragma unroll
    for (int j = 0; j < 4; ++j) {
      const int gn = n0 + wn + j * 16 + l15;
      const float bj = bias[gn];
#pragma unroll
      for (int i = 0; i < 4; ++i) {
        const int gm = m0 + wm + i * 16 + l4 * 4;
#pragma unroll
        for (int r = 0; r < 4; ++r) {
          float v = acc[i][j][r] + bj;
          if (EPI == 2) v += R[(size_t)(gm + r) * N + gn];
          Cf[(size_t)(gm + r) * N + gn] = v;
        }
      }
    }
  }
}

// ---------------- MFMA flash attention, swapped 32x32x16 + T14 prefetch -----
// Grid: 1024 blocks 1D. XCD-grouping remap: physical block p runs on XCD p&7
// (round-robin dispatch); decode so all 16 q-tiles of one (b,head) land on
// ONE XCD -> its K/V (512KB) stays in that XCD's 4MB L2 (8 groups = 4MB).
__global__ __launch_bounds__(256, 3) void attn_kernel(
    const bf16_t* __restrict__ qkv, const bf16_t* __restrict__ Vt,
    const float* __restrict__ mask, bf16_t* __restrict__ ctx) {
  __shared__ __align__(16) bf16_t K_lds[64 * 72];   // [kv][d]
  __shared__ __align__(16) bf16_t Vt_lds[64 * 72];  // [dv][kv]
  const int tid = threadIdx.x;
  const int lane = tid & 63;
  const int w = tid >> 6;
  const int l31 = lane & 31;
  const int h = lane >> 5;

  // XCD-grouping decode (bijective on 1024 blocks)
  const int p = blockIdx.x;
  const int xcd = p & 7;
  const int c = p >> 3;        // 0..127
  const int j = c & 15;        // q-tile index
  const int g = (c >> 4) * 8 + xcd;  // (b,head) group 0..63
  const int b = g >> 4;
  const int head = g & 15;
  const int q0 = j * 128;

  const int qrow = q0 + w * 32 + l31;

  bf16x8 qf[4];
  {
    const bf16_t* qp = qkv + (size_t)(b * SS + qrow) * 3072 + head * 64 + 8 * h;
#pragma unroll
    for (int ks = 0; ks < 4; ++ks) qf[ks] = *(const bf16x8*)(qp + 16 * ks);
  }

  const int srow = tid >> 2;
  const int scol = (tid & 3) * 16;
  const bf16_t* kp0 =
      qkv + (size_t)(b * SS + srow) * 3072 + 1024 + head * 64 + scol;
  const bf16_t* vp0 = Vt + ((size_t)(b * NH + head) * 64 + srow) * SS + scol;

  // prologue: load K/V tile 0 into registers
  bf16x8 kr0 = *(const bf16x8*)kp0;
  bf16x8 kr1 = *(const bf16x8*)(kp0 + 8);
  bf16x8 vr0 = *(const bf16x8*)vp0;
  bf16x8 vr1 = *(const bf16x8*)(vp0 + 8);

  float m = -3.0e38f, l = 0.0f;
  f32x16 cacc0 = {};
  f32x16 cacc1 = {};

  for (int kv0 = 0; kv0 < SS; kv0 += 64) {
    __syncthreads();  // all waves done reading previous K/V tile
    *(bf16x8*)(K_lds + srow * 72 + scol) = kr0;
    *(bf16x8*)(K_lds + srow * 72 + scol + 8) = kr1;
    *(bf16x8*)(Vt_lds + srow * 72 + scol) = vr0;
    *(bf16x8*)(Vt_lds + srow * 72 + scol + 8) = vr1;
    // T14: issue NEXT tile's loads now; latency hides under this tile's compute
    if (kv0 + 64 < SS) {
      const bf16_t* kp = kp0 + (size_t)(kv0 + 64) * 3072;
      const bf16_t* vp = vp0 + (kv0 + 64);
      kr0 = *(const bf16x8*)kp;
      kr1 = *(const bf16x8*)(kp + 8);
      vr0 = *(const bf16x8*)vp;
      vr1 = *(const bf16x8*)(vp + 8);
    }
    float4 mv[8];
#pragma unroll
    for (int k2 = 0; k2 < 8; ++k2)
      mv[k2] = *(const float4*)(mask + (size_t)b * SS + kv0 + 8 * k2 + 4 * h);
    __syncthreads();

    f32x16 sacc0 = {};
    f32x16 sacc1 = {};
#pragma unroll
    for (int ks = 0; ks < 4; ++ks) {
      const bf16x8 kf0 = *(const bf16x8*)(K_lds + l31 * 72 + 16 * ks + 8 * h);
      const bf16x8 kf1 =
          *(const bf16x8*)(K_lds + (l31 + 32) * 72 + 16 * ks + 8 * h);
      sacc0 = __builtin_amdgcn_mfma_f32_32x32x16_bf16(kf0, qf[ks], sacc0, 0, 0, 0);
      sacc1 = __builtin_amdgcn_mfma_f32_32x32x16_bf16(kf1, qf[ks], sacc1, 0, 0, 0);
    }

    float ps[32];
    float tmax = -3.0e38f;
#pragma unroll
    for (int r = 0; r < 16; ++r) {
      const float s0 = sacc0[r] * 0.125f + mv[(r >> 2)][r & 3];
      const float s1 = sacc1[r] * 0.125f + mv[(r >> 2) + 4][r & 3];
      ps[r] = s0;
      ps[16 + r] = s1;
      tmax = fmaxf(tmax, fmaxf(s0, s1));
    }
    tmax = fmaxf(tmax, __shfl_xor(tmax, 32, 64));
    if (__any(tmax > m + 8.0f)) {
      const float mnew = fmaxf(m, tmax);
      const float sc = __expf(m - mnew);
      m = mnew;
      l *= sc;
#pragma unroll
      for (int r = 0; r < 16; ++r) {
        const float scr = __shfl(sc, (r & 3) + 8 * (r >> 2) + 4 * h, 64);
        cacc0[r] *= scr;
        cacc1[r] *= scr;
      }
    }
    float ls = 0.0f;
#pragma unroll
    for (int i = 0; i < 32; ++i) {
      ps[i] = __expf(ps[i] - m);
      ls += ps[i];
    }
    l += ls + __shfl_xor(ls, 32, 64);

    unsigned pw0[8], pw1[8];
#pragma unroll
    for (int k = 0; k < 8; ++k) {
      const int base = (k >> 2) * 16 + (k & 3) * 4;
      pw0[k] = pack2_bf16(ps[base + 0], ps[base + 1]);
      pw1[k] = pack2_bf16(ps[base + 2], ps[base + 3]);
    }
#pragma unroll
    for (int t = 0; t < 4; ++t) {
      const unsigned e0 = h ? pw0[2 * t] : pw0[2 * t + 1];
      const unsigned e1 = h ? pw1[2 * t] : pw1[2 * t + 1];
      const unsigned o0 = (unsigned)__shfl_xor((int)e0, 32, 64);
      const unsigned o1 = (unsigned)__shfl_xor((int)e1, 32, 64);
      const unsigned a0 = h ? pw0[2 * t + 1] : pw0[2 * t];
      const unsigned a1 = h ? pw1[2 * t + 1] : pw1[2 * t];
      union { unsigned u[4]; bf16x8 v; } pu;
      pu.u[0] = h ? o0 : a0;
      pu.u[1] = h ? o1 : a1;
      pu.u[2] = h ? a0 : o0;
      pu.u[3] = h ? a1 : o1;
      const bf16x8 vf0 = *(const bf16x8*)(Vt_lds + l31 * 72 + 16 * t + 8 * h);
      const bf16x8 vf1 =
          *(const bf16x8*)(Vt_lds + (l31 + 32) * 72 + 16 * t + 8 * h);
      cacc0 = __builtin_amdgcn_mfma_f32_32x32x16_bf16(pu.v, vf0, cacc0, 0, 0, 0);
      cacc1 = __builtin_amdgcn_mfma_f32_32x32x16_bf16(pu.v, vf1, cacc1, 0, 0, 0);
    }
  }

  const float linv = 1.0f / l;
#pragma unroll
  for (int r = 0; r < 16; ++r) {
    const int rq = (r & 3) + 8 * (r >> 2) + 4 * h;
    const float li = __shfl(linv, rq, 64);
    const int grow = q0 + w * 32 + rq;
    bf16_t* op = ctx + (size_t)(b * SS + grow) * 1024 + head * 64 + l31;
    op[0] = (bf16_t)(cacc0[r] * li);
    op[32] = (bf16_t)(cacc1[r] * li);
  }
}

extern "C" void kernel_launch(void* const* d_in, const int* in_sizes, int n_in,
                              void* d_out, int out_size, void* d_ws, size_t ws_size,
                              hipStream_t stream) {
  const float* input    = (const float*)d_in[0];
  const float* mask     = (const float*)d_in[1];
  const float* norm_w   = (const float*)d_in[2];
  const float* norm_b   = (const float*)d_in[3];
  const float* qkv_w    = (const float*)d_in[4];
  const float* qkv_b    = (const float*)d_in[5];
  const float* attn_ow  = (const float*)d_in[6];
  const float* attn_ob  = (const float*)d_in[7];
  const float* attn_nw  = (const float*)d_in[8];
  const float* attn_nb  = (const float*)d_in[9];
  const float* inter_w  = (const float*)d_in[10];
  const float* inter_b  = (const float*)d_in[11];
  const float* output_w = (const float*)d_in[12];
  const float* output_b = (const float*)d_in[13];

  char* ws = (char*)d_ws;
  const size_t off_xln = 0;
  const size_t off_qkv = 16777216;
  const size_t off_vt  = 67108864;
  const size_t off_ctx = 83886080;
  const size_t off_ao  = 100663296;
  const size_t off_wq  = 134217728;
  const size_t off_wo  = 140509184;
  const size_t off_wi  = 142606336;
  const size_t off_w2  = 150994944;
  const size_t NEED    = 159383552;
  if (ws_size < NEED) return;

  bf16_t* x_ln  = (bf16_t*)(ws + off_xln);
  bf16_t* qkvb  = (bf16_t*)(ws + off_qkv);
  bf16_t* VtB   = (bf16_t*)(ws + off_vt);
  bf16_t* ctxb  = (bf16_t*)(ws + off_ctx);
  bf16_t* y_ln  = (bf16_t*)(ws + off_ctx);
  float*  a_out = (float*)(ws + off_ao);
  bf16_t* wq_t  = (bf16_t*)(ws + off_wq);
  bf16_t* wo_t  = (bf16_t*)(ws + off_wo);
  bf16_t* wi_t  = (bf16_t*)(ws + off_wi);
  bf16_t* w2_t  = (bf16_t*)(ws + off_w2);
  bf16_t* act   = (bf16_t*)(ws + off_xln);

  const int M = BB * SS;  // 8192

  wt_kernel<<<dim3(3072 / 32, 1024 / 32), 256, 0, stream>>>(qkv_w, wq_t, 1024, 3072);
  wt_kernel<<<dim3(1024 / 32, 1024 / 32), 256, 0, stream>>>(attn_ow, wo_t, 1024, 1024);
  wt_kernel<<<dim3(4096 / 32, 1024 / 32), 256, 0, stream>>>(inter_w, wi_t, 1024, 4096);
  wt_kernel<<<dim3(1024 / 32, 4096 / 32), 256, 0, stream>>>(output_w, w2_t, 4096, 1024);

  ln_kernel<<<M, 256, 0, stream>>>(input, norm_w, norm_b, x_ln);
  gemm_bf16<0, true><<<dim3(3072 / 128, M / 128), 256, 0, stream>>>(
      x_ln, wq_t, qkv_b, nullptr, qkvb, M, 3072, 1024);
  vtrans_kernel<<<dim3(SS / 256, NH, BB), 256, 0, stream>>>(qkvb, VtB);
  attn_kernel<<<1024, 256, 0, stream>>>(qkvb, VtB, mask, ctxb);
  gemm_bf16<2, false><<<dim3(1024 / 128, M / 128), 256, 0, stream>>>(
      ctxb, wo_t, attn_ob, input, a_out, M, 1024, 1024);
  ln_kernel<<<M, 256, 0, stream>>>(a_out, attn_nw, attn_nb, y_ln);
  gemm_bf16<1, true><<<dim3(4096 / 128, M / 128), 256, 0, stream>>>(
      y_ln, wi_t, inter_b, nullptr, act, M, 4096, 1024);
  gemm_bf16<2, false><<<dim3(1024 / 128, M / 128), 256, 0, stream>>>(
      act, w2_t, output_b, a_out, (float*)d_out, M, 1024, 4096);
}

// Round 17
// 457.478 us; speedup vs baseline: 1.0311x; 1.0096x over previous
//
#include <hip/hip_runtime.h>
#include <math.h>

typedef __bf16 bf16_t;
typedef bf16_t bf16x8 __attribute__((ext_vector_type(8)));
typedef bf16_t bf16x4 __attribute__((ext_vector_type(4)));
typedef float f32x4 __attribute__((ext_vector_type(4)));
typedef float f32x16 __attribute__((ext_vector_type(16)));

#define BB 4
#define SS 2048
#define HD1 1024
#define NH 16
#define DFF_ 4096

__device__ __forceinline__ void gload_lds16(const bf16_t* g, bf16_t* l) {
  __builtin_amdgcn_global_load_lds(
      (const __attribute__((address_space(1))) void*)g,
      (__attribute__((address_space(3))) void*)l, 16, 0, 0);
}

// single-instruction f32x2 -> packed bf16 (T12 recipe; no builtin on gfx950)
__device__ __forceinline__ unsigned pack2_bf16(float a, float b) {
  unsigned r;
  asm("v_cvt_pk_bf16_f32 %0, %1, %2" : "=v"(r) : "v"(a), "v"(b));
  return r;
}

// ---------------- LayerNorm: fp32 in -> bf16 out, one block per row ---------
__device__ __forceinline__ float block_reduce_sum(float v, float* red) {
  const int lane = threadIdx.x & 63;
  const int wid = threadIdx.x >> 6;
#pragma unroll
  for (int off = 32; off > 0; off >>= 1) v += __shfl_down(v, off, 64);
  if (lane == 0) red[wid] = v;
  __syncthreads();
  float s = red[0] + red[1] + red[2] + red[3];
  __syncthreads();
  return s;
}

__global__ __launch_bounds__(256) void ln_kernel(const float* __restrict__ x,
                                                 const float* __restrict__ w,
                                                 const float* __restrict__ bv,
                                                 bf16_t* __restrict__ out) {
  __shared__ float red[4];
  const size_t row = blockIdx.x;
  const float4 xv = *(const float4*)(x + row * HD1 + threadIdx.x * 4);
  float s = xv.x + xv.y + xv.z + xv.w;
  s = block_reduce_sum(s, red);
  const float mu = s * (1.0f / HD1);
  float4 d;
  d.x = xv.x - mu; d.y = xv.y - mu; d.z = xv.z - mu; d.w = xv.w - mu;
  float sq = d.x * d.x + d.y * d.y + d.z * d.z + d.w * d.w;
  sq = block_reduce_sum(sq, red);
  const float rs = rsqrtf(sq * (1.0f / HD1) + 1e-12f);
  const float4 wv = *(const float4*)(w + threadIdx.x * 4);
  const float4 bb = *(const float4*)(bv + threadIdx.x * 4);
  bf16x4 o;
  o[0] = (bf16_t)(d.x * rs * wv.x + bb.x);
  o[1] = (bf16_t)(d.y * rs * wv.y + bb.y);
  o[2] = (bf16_t)(d.z * rs * wv.z + bb.z);
  o[3] = (bf16_t)(d.w * rs * wv.w + bb.w);
  *(bf16x4*)(out + row * HD1 + threadIdx.x * 4) = o;
}

// ---------------- Weight convert+transpose: W[K][N] f32 -> Wt[N][K] bf16 ----
__global__ __launch_bounds__(256) void wt_kernel(const float* __restrict__ W,
                                                 bf16_t* __restrict__ Wt,
                                                 int K, int N) {
  __shared__ bf16_t T[32][33];
  const int t = threadIdx.x;
  const int n0 = blockIdx.x * 32, k0 = blockIdx.y * 32;
  const int a = t >> 5, c = t & 31;
#pragma unroll
  for (int i = 0; i < 4; ++i) {
    const int kl = a + i * 8;
    T[kl][c] = (bf16_t)W[(size_t)(k0 + kl) * N + n0 + c];
  }
  __syncthreads();
#pragma unroll
  for (int i = 0; i < 4; ++i) {
    const int nl = a + i * 8;
    Wt[(size_t)(n0 + nl) * K + k0 + c] = T[c][nl];
  }
}

// ---------------- MFMA GEMM, BK=64 double-buffered + 8-chunk XOR swizzle ----
// (round-10/14 measured best). VF: for V-region blocks (n0>=2048, block-
// uniform) of the qkv GEMM, skip the LDS epilogue and store the accumulators
// DIRECTLY TRANSPOSED to Vout[(b*16+head)*64+d][s] -- each lane's acc[i][j]
// is 4 s-contiguous elems of one (head,d) column (8B aligned run).
template <int EPI, bool OBF, bool VF>
__global__ __launch_bounds__(256) void gemm_bf16(
    const bf16_t* __restrict__ A, const bf16_t* __restrict__ Wt,
    const float* __restrict__ bias, const float* __restrict__ R,
    void* __restrict__ Cout, bf16_t* __restrict__ Vout,
    int M, int N, int K) {
  __shared__ __align__(16) char smem[65536];
  bf16_t* As = (bf16_t*)smem;              // [2][128*64]
  bf16_t* Bs = (bf16_t*)(smem + 32768);    // [2][128*64]
  const int tid = threadIdx.x;
  const int lane = tid & 63;
  const int w = tid >> 6;
  const int wm = (w >> 1) * 64, wn = (w & 1) * 64;
  const int l15 = lane & 15, l4 = lane >> 4;

  const int gx = gridDim.x;
  int id = blockIdx.x + gx * blockIdx.y;
  const int cpx = (gx * gridDim.y) >> 3;
  id = (id & 7) * cpx + (id >> 3);
  const int m0 = (id / gx) * 128;
  const int n0 = (id % gx) * 128;

  const int lrow = tid >> 3;
  const int lcol = (((tid & 7) ^ ((tid >> 3) & 7)) * 8);
  const bf16_t* Ag = A + (size_t)(m0 + lrow) * K + lcol;
  const bf16_t* Bg = Wt + (size_t)(n0 + lrow) * K + lcol;
  const size_t rstride = (size_t)32 * K;

#pragma unroll
  for (int c = 0; c < 4; ++c) {
    gload_lds16(Ag + c * rstride, As + c * 2048 + w * 512);
    gload_lds16(Bg + c * rstride, Bs + c * 2048 + w * 512);
  }

  const int NT = K >> 6;
  f32x4 acc[4][4] = {};

  const int ch0 = (((0 * 4 + l4) ^ (l15 & 7)) * 8);
  const int ch1 = (((1 * 4 + l4) ^ (l15 & 7)) * 8);

  for (int t = 0; t < NT; ++t) {
    const int cur = t & 1;
    __syncthreads();
    if (t + 1 < NT) {
      const bf16_t* Agn = Ag + (size_t)(t + 1) * 64;
      const bf16_t* Bgn = Bg + (size_t)(t + 1) * 64;
      bf16_t* Ad = As + (cur ^ 1) * 8192;
      bf16_t* Bd = Bs + (cur ^ 1) * 8192;
#pragma unroll
      for (int c = 0; c < 4; ++c) {
        gload_lds16(Agn + c * rstride, Ad + c * 2048 + w * 512);
        gload_lds16(Bgn + c * rstride, Bd + c * 2048 + w * 512);
      }
    }
    const bf16_t* Ab = As + cur * 8192;
    const bf16_t* Bb = Bs + cur * 8192;
    bf16x8 af[2][4], bfr[2][4];
#pragma unroll
    for (int i = 0; i < 4; ++i) {
      af[0][i] = *(const bf16x8*)(Ab + (wm + i * 16 + l15) * 64 + ch0);
      af[1][i] = *(const bf16x8*)(Ab + (wm + i * 16 + l15) * 64 + ch1);
    }
#pragma unroll
    for (int j = 0; j < 4; ++j) {
      bfr[0][j] = *(const bf16x8*)(Bb + (wn + j * 16 + l15) * 64 + ch0);
      bfr[1][j] = *(const bf16x8*)(Bb + (wn + j * 16 + l15) * 64 + ch1);
    }
#pragma unroll
    for (int ks = 0; ks < 2; ++ks)
#pragma unroll
      for (int i = 0; i < 4; ++i)
#pragma unroll
        for (int j = 0; j < 4; ++j)
          acc[i][j] = __builtin_amdgcn_mfma_f32_16x16x32_bf16(
              af[ks][i], bfr[ks][j], acc[i][j], 0, 0, 0);
  }

  if (VF && n0 >= 2048) {
    // V-region block of qkv: direct transposed store, no LDS round-trip.
    // col -> (head,d); lane's 4 acc elems (r) are s-contiguous.
#pragma unroll
    for (int j = 0; j < 4; ++j) {
      const int col = wn + j * 16 + l15;
      const int hd = n0 + col - 2048;            // head*64 + d
      const float bj = bias[n0 + col];
#pragma unroll
      for (int i = 0; i < 4; ++i) {
        const int gm = m0 + wm + i * 16 + l4 * 4;
        const int bb2 = gm >> 11;                // batch
        const int sl = gm & 2047;                // s within batch
        bf16x4 tv;
#pragma unroll
        for (int r = 0; r < 4; ++r) tv[r] = (bf16_t)(acc[i][j][r] + bj);
        *(bf16x4*)(Vout + ((size_t)(bb2 * NH) * 64 + hd) * SS + sl) = tv;
      }
    }
    // also keep qkvb's V section written for layout uniformity (cheap):
    // skipped -- attention never reads it.
  } else if (OBF) {
    __syncthreads();
    float* Cs = (float*)smem;  // 128 x 128 f32 = 64 KiB
#pragma unroll
    for (int j = 0; j < 4; ++j) {
      const float bj = bias[n0 + wn + j * 16 + l15];
#pragma unroll
      for (int i = 0; i < 4; ++i)
#pragma unroll
        for (int r = 0; r < 4; ++r) {
          float v = acc[i][j][r] + bj;
          if (EPI == 1)
            v = 0.5f * v * (1.0f + erff(v * 0.70710678118654752440f));
          Cs[(wm + i * 16 + l4 * 4 + r) * 128 + wn + j * 16 + l15] = v;
        }
    }
    __syncthreads();
    bf16_t* Cb = (bf16_t*)Cout;
#pragma unroll
    for (int p = 0; p < 16; ++p) {
      const int idx = p * 256 + tid;
      const int row = idx >> 5, c4 = idx & 31;
      const f32x4 v = *(const f32x4*)(Cs + row * 128 + c4 * 4);
      bf16x4 o;
      o[0] = (bf16_t)v[0]; o[1] = (bf16_t)v[1];
      o[2] = (bf16_t)v[2]; o[3] = (bf16_t)v[3];
      *(bf16x4*)(Cb + (size_t)(m0 + row) * N + n0 + c4 * 4) = o;
    }
  } else {
    float* Cf = (float*)Cout;
#pragma unroll
    for (int j = 0; j < 4; ++j) {
      const int gn = n0 + wn + j * 16 + l15;
      const float bj = bias[gn];
#pragma unroll
      for (int i = 0; i < 4; ++i) {
        const int gm = m0 + wm + i * 16 + l4 * 4;
#pragma unroll
        for (int r = 0; r < 4; ++r) {
          float v = acc[i][j][r] + bj;
          if (EPI == 2) v += R[(size_t)(gm + r) * N + gn];
          Cf[(size_t)(gm + r) * N + gn] = v;
        }
      }
    }
  }
}

// ---------------- MFMA flash attention, swapped 32x32x16 + T14 prefetch -----
// Grid: 1024 blocks 1D. XCD-grouping remap: physical block p runs on XCD p&7
// (round-robin dispatch); decode so all 16 q-tiles of one (b,head) land on
// ONE XCD -> its K/V (512KB) stays in that XCD's 4MB L2 (8 groups = 4MB).
__global__ __launch_bounds__(256, 3) void attn_kernel(
    const bf16_t* __restrict__ qkv, const bf16_t* __restrict__ Vt,
    const float* __restrict__ mask, bf16_t* __restrict__ ctx) {
  __shared__ __align__(16) bf16_t K_lds[64 * 72];   // [kv][d]
  __shared__ __align__(16) bf16_t Vt_lds[64 * 72];  // [dv][kv]
  const int tid = threadIdx.x;
  const int lane = tid & 63;
  const int w = tid >> 6;
  const int l31 = lane & 31;
  const int h = lane >> 5;

  // XCD-grouping decode (bijective on 1024 blocks)
  const int p = blockIdx.x;
  const int xcd = p & 7;
  const int c = p >> 3;        // 0..127
  const int j = c & 15;        // q-tile index
  const int g = (c >> 4) * 8 + xcd;  // (b,head) group 0..63
  const int b = g >> 4;
  const int head = g & 15;
  const int q0 = j * 128;

  const int qrow = q0 + w * 32 + l31;

  bf16x8 qf[4];
  {
    const bf16_t* qp = qkv + (size_t)(b * SS + qrow) * 3072 + head * 64 + 8 * h;
#pragma unroll
    for (int ks = 0; ks < 4; ++ks) qf[ks] = *(const bf16x8*)(qp + 16 * ks);
  }

  const int srow = tid >> 2;
  const int scol = (tid & 3) * 16;
  const bf16_t* kp0 =
      qkv + (size_t)(b * SS + srow) * 3072 + 1024 + head * 64 + scol;
  const bf16_t* vp0 = Vt + ((size_t)(b * NH + head) * 64 + srow) * SS + scol;

  // prologue: load K/V tile 0 into registers
  bf16x8 kr0 = *(const bf16x8*)kp0;
  bf16x8 kr1 = *(const bf16x8*)(kp0 + 8);
  bf16x8 vr0 = *(const bf16x8*)vp0;
  bf16x8 vr1 = *(const bf16x8*)(vp0 + 8);

  float m = -3.0e38f, l = 0.0f;
  f32x16 cacc0 = {};
  f32x16 cacc1 = {};

  for (int kv0 = 0; kv0 < SS; kv0 += 64) {
    __syncthreads();  // all waves done reading previous K/V tile
    *(bf16x8*)(K_lds + srow * 72 + scol) = kr0;
    *(bf16x8*)(K_lds + srow * 72 + scol + 8) = kr1;
    *(bf16x8*)(Vt_lds + srow * 72 + scol) = vr0;
    *(bf16x8*)(Vt_lds + srow * 72 + scol + 8) = vr1;
    // T14: issue NEXT tile's loads now; latency hides under this tile's compute
    if (kv0 + 64 < SS) {
      const bf16_t* kp = kp0 + (size_t)(kv0 + 64) * 3072;
      const bf16_t* vp = vp0 + (kv0 + 64);
      kr0 = *(const bf16x8*)kp;
      kr1 = *(const bf16x8*)(kp + 8);
      vr0 = *(const bf16x8*)vp;
      vr1 = *(const bf16x8*)(vp + 8);
    }
    float4 mv[8];
#pragma unroll
    for (int k2 = 0; k2 < 8; ++k2)
      mv[k2] = *(const float4*)(mask + (size_t)b * SS + kv0 + 8 * k2 + 4 * h);
    __syncthreads();

    f32x16 sacc0 = {};
    f32x16 sacc1 = {};
#pragma unroll
    for (int ks = 0; ks < 4; ++ks) {
      const bf16x8 kf0 = *(const bf16x8*)(K_lds + l31 * 72 + 16 * ks + 8 * h);
      const bf16x8 kf1 =
          *(const bf16x8*)(K_lds + (l31 + 32) * 72 + 16 * ks + 8 * h);
      sacc0 = __builtin_amdgcn_mfma_f32_32x32x16_bf16(kf0, qf[ks], sacc0, 0, 0, 0);
      sacc1 = __builtin_amdgcn_mfma_f32_32x32x16_bf16(kf1, qf[ks], sacc1, 0, 0, 0);
    }

    float ps[32];
    float tmax = -3.0e38f;
#pragma unroll
    for (int r = 0; r < 16; ++r) {
      const float s0 = sacc0[r] * 0.125f + mv[(r >> 2)][r & 3];
      const float s1 = sacc1[r] * 0.125f + mv[(r >> 2) + 4][r & 3];
      ps[r] = s0;
      ps[16 + r] = s1;
      tmax = fmaxf(tmax, fmaxf(s0, s1));
    }
    tmax = fmaxf(tmax, __shfl_xor(tmax, 32, 64));
    if (__any(tmax > m + 8.0f)) {
      const float mnew = fmaxf(m, tmax);
      const float sc = __expf(m - mnew);
      m = mnew;
      l *= sc;
#pragma unroll
      for (int r = 0; r < 16; ++r) {
        const float scr = __shfl(sc, (r & 3) + 8 * (r >> 2) + 4 * h, 64);
        cacc0[r] *= scr;
        cacc1[r] *= scr;
      }
    }
    float ls = 0.0f;
#pragma unroll
    for (int i = 0; i < 32; ++i) {
      ps[i] = __expf(ps[i] - m);
      ls += ps[i];
    }
    l += ls + __shfl_xor(ls, 32, 64);

    unsigned pw0[8], pw1[8];
#pragma unroll
    for (int k = 0; k < 8; ++k) {
      const int base = (k >> 2) * 16 + (k & 3) * 4;
      pw0[k] = pack2_bf16(ps[base + 0], ps[base + 1]);
      pw1[k] = pack2_bf16(ps[base + 2], ps[base + 3]);
    }
#pragma unroll
    for (int t = 0; t < 4; ++t) {
      const unsigned e0 = h ? pw0[2 * t] : pw0[2 * t + 1];
      const unsigned e1 = h ? pw1[2 * t] : pw1[2 * t + 1];
      const unsigned o0 = (unsigned)__shfl_xor((int)e0, 32, 64);
      const unsigned o1 = (unsigned)__shfl_xor((int)e1, 32, 64);
      const unsigned a0 = h ? pw0[2 * t + 1] : pw0[2 * t];
      const unsigned a1 = h ? pw1[2 * t + 1] : pw1[2 * t];
      union { unsigned u[4]; bf16x8 v; } pu;
      pu.u[0] = h ? o0 : a0;
      pu.u[1] = h ? o1 : a1;
      pu.u[2] = h ? a0 : o0;
      pu.u[3] = h ? a1 : o1;
      const bf16x8 vf0 = *(const bf16x8*)(Vt_lds + l31 * 72 + 16 * t + 8 * h);
      const bf16x8 vf1 =
          *(const bf16x8*)(Vt_lds + (l31 + 32) * 72 + 16 * t + 8 * h);
      cacc0 = __builtin_amdgcn_mfma_f32_32x32x16_bf16(pu.v, vf0, cacc0, 0, 0, 0);
      cacc1 = __builtin_amdgcn_mfma_f32_32x32x16_bf16(pu.v, vf1, cacc1, 0, 0, 0);
    }
  }

  const float linv = 1.0f / l;
#pragma unroll
  for (int r = 0; r < 16; ++r) {
    const int rq = (r & 3) + 8 * (r >> 2) + 4 * h;
    const float li = __shfl(linv, rq, 64);
    const int grow = q0 + w * 32 + rq;
    bf16_t* op = ctx + (size_t)(b * SS + grow) * 1024 + head * 64 + l31;
    op[0] = (bf16_t)(cacc0[r] * li);
    op[32] = (bf16_t)(cacc1[r] * li);
  }
}

extern "C" void kernel_launch(void* const* d_in, const int* in_sizes, int n_in,
                              void* d_out, int out_size, void* d_ws, size_t ws_size,
                              hipStream_t stream) {
  const float* input    = (const float*)d_in[0];
  const float* mask     = (const float*)d_in[1];
  const float* norm_w   = (const float*)d_in[2];
  const float* norm_b   = (const float*)d_in[3];
  const float* qkv_w    = (const float*)d_in[4];
  const float* qkv_b    = (const float*)d_in[5];
  const float* attn_ow  = (const float*)d_in[6];
  const float* attn_ob  = (const float*)d_in[7];
  const float* attn_nw  = (const float*)d_in[8];
  const float* attn_nb  = (const float*)d_in[9];
  const float* inter_w  = (const float*)d_in[10];
  const float* inter_b  = (const float*)d_in[11];
  const float* output_w = (const float*)d_in[12];
  const float* output_b = (const float*)d_in[13];

  char* ws = (char*)d_ws;
  const size_t off_xln = 0;
  const size_t off_qkv = 16777216;
  const size_t off_vt  = 67108864;
  const size_t off_ctx = 83886080;
  const size_t off_ao  = 100663296;
  const size_t off_wq  = 134217728;
  const size_t off_wo  = 140509184;
  const size_t off_wi  = 142606336;
  const size_t off_w2  = 150994944;
  const size_t NEED    = 159383552;
  if (ws_size < NEED) return;

  bf16_t* x_ln  = (bf16_t*)(ws + off_xln);
  bf16_t* qkvb  = (bf16_t*)(ws + off_qkv);
  bf16_t* VtB   = (bf16_t*)(ws + off_vt);
  bf16_t* ctxb  = (bf16_t*)(ws + off_ctx);
  bf16_t* y_ln  = (bf16_t*)(ws + off_ctx);
  float*  a_out = (float*)(ws + off_ao);
  bf16_t* wq_t  = (bf16_t*)(ws + off_wq);
  bf16_t* wo_t  = (bf16_t*)(ws + off_wo);
  bf16_t* wi_t  = (bf16_t*)(ws + off_wi);
  bf16_t* w2_t  = (bf16_t*)(ws + off_w2);
  bf16_t* act   = (bf16_t*)(ws + off_xln);

  const int M = BB * SS;  // 8192

  wt_kernel<<<dim3(3072 / 32, 1024 / 32), 256, 0, stream>>>(qkv_w, wq_t, 1024, 3072);
  wt_kernel<<<dim3(1024 / 32, 1024 / 32), 256, 0, stream>>>(attn_ow, wo_t, 1024, 1024);
  wt_kernel<<<dim3(4096 / 32, 1024 / 32), 256, 0, stream>>>(inter_w, wi_t, 1024, 4096);
  wt_kernel<<<dim3(1024 / 32, 4096 / 32), 256, 0, stream>>>(output_w, w2_t, 4096, 1024);

  ln_kernel<<<M, 256, 0, stream>>>(input, norm_w, norm_b, x_ln);
  // qkv GEMM with fused V-transpose epilogue (vtrans kernel eliminated)
  gemm_bf16<0, true, true><<<dim3(3072 / 128, M / 128), 256, 0, stream>>>(
      x_ln, wq_t, qkv_b, nullptr, qkvb, VtB, M, 3072, 1024);
  attn_kernel<<<1024, 256, 0, stream>>>(qkvb, VtB, mask, ctxb);
  gemm_bf16<2, false, false><<<dim3(1024 / 128, M / 128), 256, 0, stream>>>(
      ctxb, wo_t, attn_ob, input, a_out, nullptr, M, 1024, 1024);
  ln_kernel<<<M, 256, 0, stream>>>(a_out, attn_nw, attn_nb, y_ln);
  gemm_bf16<1, true, false><<<dim3(4096 / 128, M / 128), 256, 0, stream>>>(
      y_ln, wi_t, inter_b, nullptr, act, nullptr, M, 4096, 1024);
  gemm_bf16<2, false, false><<<dim3(1024 / 128, M / 128), 256, 0, stream>>>(
      act, w2_t, output_b, a_out, (float*)d_out, nullptr, M, 1024, 4096);
}